// Round 14
// baseline (133.161 us; speedup 1.0000x reference)
//
#include <hip/hip_runtime.h>
#include <hip/hip_bf16.h>
#include <math.h>

// Dims: B=4, T=1024, H=W=64, C=256, nh=8, hd=32
using bf16x8 = __attribute__((ext_vector_type(8))) short;
using f32x4  = __attribute__((ext_vector_type(4))) float;
using s16x4  = __attribute__((ext_vector_type(4))) short;

static __device__ __forceinline__ float sigmoidf_(float x){ return 1.f/(1.f+__expf(-x)); }
static __device__ __forceinline__ unsigned f2bfu(float f){
  union { float f; unsigned u; } x; x.f = f;
  return (x.u + 0x7FFFu + ((x.u>>16)&1u)) >> 16;
}
static __device__ __forceinline__ short f2bf(float f){ return (short)f2bfu(f); }
// packed bf16 convert: single v_cvt_pk_bf16_f32 (RNE), low short = first arg
static __device__ __forceinline__ unsigned pack2bf(float lo, float hi){
  __hip_bfloat162 h = __float22bfloat162_rn(make_float2(lo, hi));
  unsigned r; __builtin_memcpy(&r, &h, 4);
  return r;
}
static __device__ __forceinline__ float b2f_lo(unsigned u){ union{unsigned u; float f;}x; x.u = u<<16; return x.f; }
static __device__ __forceinline__ float b2f_hi(unsigned u){ union{unsigned u; float f;}x; x.u = u & 0xFFFF0000u; return x.f; }

// ---------------- bf16 MFMA GEMM body ----------------
// mode 0: *scale ; mode 3: transposed [t][b][c] store ; mode 4: value-proj -> vpB bf16 [bn][w][d][h]
__device__ __forceinline__ void mfma_body(short* As, short* Bs,
    const float* __restrict__ X, const float* __restrict__ Wm,
    const float* __restrict__ bias, float* __restrict__ Y,
    int bxm, int bxn, float scale, int mode){
  int tid = threadIdx.x;
  int m0 = bxm*128, n0 = bxn*128;
  int l = tid&63, wid = tid>>6, lo16 = l&15, g = l>>4;
  int wm = wid>>1, wn = wid&1;
  f32x4 acc[4][4] = {};
  int srow = tid>>1, skq = (tid&1)*32;
  size_t arow;
  int vb_ = 0, vw0 = 0;
  if (mode==4){
    vb_ = bxm>>5; vw0 = (bxm&31)*2;
    arow = (size_t)(vb_*4096 + (srow&63)*64 + vw0 + (srow>>6));
  } else arow = (size_t)(m0+srow);
  const float4* sa = (const float4*)(X + arow*256 + skq);
  const float4* sb = (const float4*)(Wm + (size_t)(n0+srow)*256 + skq);
  int4* da = (int4*)&As[srow*72 + skq];
  int4* db = (int4*)&Bs[srow*72 + skq];
  for (int k0=0;k0<4;k0++){
    __syncthreads();
    #pragma unroll
    for (int j=0;j<4;j++){
      float4 v0 = sa[2*j], v1 = sa[2*j+1];
      int4 wv;
      wv.x = (int)pack2bf(v0.x, v0.y); wv.y = (int)pack2bf(v0.z, v0.w);
      wv.z = (int)pack2bf(v1.x, v1.y); wv.w = (int)pack2bf(v1.z, v1.w);
      da[j] = wv;
      float4 u0 = sb[2*j], u1 = sb[2*j+1];
      int4 xv;
      xv.x = (int)pack2bf(u0.x, u0.y); xv.y = (int)pack2bf(u0.z, u0.w);
      xv.z = (int)pack2bf(u1.x, u1.y); xv.w = (int)pack2bf(u1.z, u1.w);
      db[j] = xv;
    }
    sa += 16; sb += 16;
    __syncthreads();
    bf16x8 af[4][2], bfr[4][2];
    #pragma unroll
    for (int mt=0;mt<4;mt++)
      #pragma unroll
      for (int c=0;c<2;c++)
        af[mt][c] = *(const bf16x8*)&As[(wm*64 + mt*16 + lo16)*72 + c*32 + g*8];
    #pragma unroll
    for (int nt=0;nt<4;nt++)
      #pragma unroll
      for (int c=0;c<2;c++)
        bfr[nt][c] = *(const bf16x8*)&Bs[(wn*64 + nt*16 + lo16)*72 + c*32 + g*8];
    #pragma unroll
    for (int mt=0;mt<4;mt++)
      #pragma unroll
      for (int nt=0;nt<4;nt++){
        acc[mt][nt] = __builtin_amdgcn_mfma_f32_16x16x32_bf16(af[mt][0], bfr[nt][0], acc[mt][nt], 0,0,0);
        acc[mt][nt] = __builtin_amdgcn_mfma_f32_16x16x32_bf16(af[mt][1], bfr[nt][1], acc[mt][nt], 0,0,0);
      }
  }
  if (mode==4){
    short* vdst = (short*)Y;
    int w = vw0 + wm;
    #pragma unroll
    for (int nt=0;nt<4;nt++){
      int col = n0 + wn*64 + nt*16 + lo16;
      float bv = bias[col];
      int n = col>>5, d = col&31;
      size_t base = (size_t)(vb_*8+n)*131072 + (size_t)w*2048 + d*64;
      #pragma unroll
      for (int mt=0;mt<4;mt++){
        int h0 = mt*16 + g*4;
        s16x4 s;
        #pragma unroll
        for (int r=0;r<4;r++) s[r] = f2bf(acc[mt][nt][r] + bv);
        *(s16x4*)(vdst + base + h0) = s;
      }
    }
  } else if (mode==3){
    #pragma unroll
    for (int nt=0;nt<4;nt++){
      int col = n0 + wn*64 + nt*16 + lo16;
      float bv = bias[col];
      #pragma unroll
      for (int mt=0;mt<4;mt++){
        int row = m0 + wm*64 + mt*16 + g*4;
        #pragma unroll
        for (int r=0;r<4;r++){
          int rr = row + r;
          Y[((size_t)((rr&1023)*4 + (rr>>10)))*256 + col] = acc[mt][nt][r] + bv;
        }
      }
    }
  } else {
    #pragma unroll
    for (int nt=0;nt<4;nt++){
      int col = n0 + wn*64 + nt*16 + lo16;
      float bv = bias[col];
      #pragma unroll
      for (int mt=0;mt<4;mt++){
        int row = m0 + wm*64 + mt*16 + g*4;
        #pragma unroll
        for (int r=0;r<4;r++){
          float y = acc[mt][nt][r] + bv;
          if (mode==0) y *= scale;
          Y[(size_t)(row+r)*256 + col] = y;
        }
      }
    }
  }
}

// ---------------- L1: reductions + fused kr0/kc0 GEMM (640 blocks) ----------------
// bx<128: vpart. bx in [128,384): krm row -> kr0 = krm@W2^T+b (ungated).
// bx in [384,640): kcm row -> kc0 = kcm@W3^T+b (ungated).
__global__ __launch_bounds__(256) void k_reduce(
    const float* __restrict__ value, const float* __restrict__ key_row,
    const float* __restrict__ key_col, const float* __restrict__ ipw,
    const float* __restrict__ ipb,
    float* __restrict__ vpart, float* __restrict__ kr0, float* __restrict__ kc0){
  __shared__ float red[1024];
  __shared__ float row[256];
  int bx = blockIdx.x, c = threadIdx.x;
  int cq = c & 63, rg = c >> 6;
  float4 s4 = make_float4(0.f,0.f,0.f,0.f);
  if (bx < 128){
    int b = bx >> 5, chunk = bx & 31;
    const float4* p = (const float4*)(value + ((size_t)(b*4096 + chunk*128 + rg))*256) + cq;
    #pragma unroll 8
    for (int i=0;i<32;i++){
      float4 v = p[(size_t)i*256];
      s4.x+=v.x; s4.y+=v.y; s4.z+=v.z; s4.w+=v.w;
    }
    *(float4*)&red[rg*256 + cq*4] = s4;
    __syncthreads();
    if (c < 64){
      float4 a0 = *(float4*)&red[c*4];
      float4 a1 = *(float4*)&red[256 + c*4];
      float4 a2 = *(float4*)&red[512 + c*4];
      float4 a3 = *(float4*)&red[768 + c*4];
      *(float4*)&vpart[(size_t)bx*256 + c*4] =
        make_float4(a0.x+a1.x+a2.x+a3.x, a0.y+a1.y+a2.y+a3.y,
                    a0.z+a1.z+a2.z+a3.z, a0.w+a1.w+a2.w+a3.w);
    }
    return;
  }
  const float* Wm; const float* bias; float* Y; int idx;
  if (bx < 384){
    idx = bx - 128;
    int b = idx >> 6, w = idx & 63;
    const float4* p = (const float4*)(key_row + ((size_t)(b*4096 + w))*256) + cq;
    #pragma unroll 8
    for (int i=0;i<16;i++){
      float4 v = p[(size_t)(rg + 4*i)*4096];
      s4.x+=v.x; s4.y+=v.y; s4.z+=v.z; s4.w+=v.w;
    }
    Wm = ipw + 131072; bias = ipb + 512; Y = kr0;
  } else {
    idx = bx - 384;
    int b = idx >> 6, h = idx & 63;
    const float4* p = (const float4*)(key_col + ((size_t)((b*64+h)*64))*256) + cq;
    #pragma unroll 8
    for (int i=0;i<16;i++){
      float4 v = p[(size_t)(rg + 4*i)*64];
      s4.x+=v.x; s4.y+=v.y; s4.z+=v.z; s4.w+=v.w;
    }
    Wm = ipw + 196608; bias = ipb + 768; Y = kc0;
  }
  *(float4*)&red[rg*256 + cq*4] = s4;
  __syncthreads();
  if (c < 64){
    float4 a0 = *(float4*)&red[c*4];
    float4 a1 = *(float4*)&red[256 + c*4];
    float4 a2 = *(float4*)&red[512 + c*4];
    float4 a3 = *(float4*)&red[768 + c*4];
    const float inv = 1.f/64.f;
    *(float4*)&row[c*4] =
      make_float4((a0.x+a1.x+a2.x+a3.x)*inv, (a0.y+a1.y+a2.y+a3.y)*inv,
                  (a0.z+a1.z+a2.z+a3.z)*inv, (a0.w+a1.w+a2.w+a3.w)*inv);
  }
  __syncthreads();
  // per-thread dot: Y[idx][c] = row . Wm[c,:] + bias[c]
  {
    const float4* wr = (const float4*)(Wm + (size_t)c*256);
    const float4* rv = (const float4*)row;
    float acc = bias[c];
    #pragma unroll 8
    for (int k=0;k<64;k++){
      float4 w4 = wr[k]; float4 v4 = rv[k];
      acc += w4.x*v4.x + w4.y*v4.y + w4.z*v4.z + w4.w*v4.w;
    }
    Y[(size_t)idx*256 + c] = acc;
  }
}

// ---------------- L2: gate (bx<4) || qr/qc MFMA (4..131) || vp MFMA (132..387) ----------------
__global__ __launch_bounds__(256) void k_proj(
    const float* __restrict__ value,
    const float* __restrict__ query_row, const float* __restrict__ query_col,
    const float* __restrict__ ipw, const float* __restrict__ ipb,
    const float* __restrict__ vpart, const float* __restrict__ lin_w,
    const float* __restrict__ lin_b,
    float* __restrict__ gate,
    float* __restrict__ qr, float* __restrict__ qc,
    short* __restrict__ vpB, float scaling){
  __shared__ __align__(16) char smem[36864];
  int bx = blockIdx.x;
  if (bx < 4){
    float* va = (float*)smem;
    int b = bx, c = threadIdx.x;
    float s = 0.f;
    #pragma unroll
    for (int i=0;i<32;i++) s += vpart[(size_t)(b*32+i)*256 + c];
    va[c] = s * (1.f/4096.f);
    __syncthreads();
    const float4* wr  = (const float4*)(lin_w + (size_t)c*256);
    const float4* vp4 = (const float4*)va;
    float acc = lin_b[c];
    #pragma unroll 8
    for (int k=0;k<64;k++){
      float4 w4 = wr[k]; float4 v4 = vp4[k];
      acc += w4.x*v4.x + w4.y*v4.y + w4.z*v4.z + w4.w*v4.w;
    }
    gate[b*256+c] = sigmoidf_(acc);
    return;
  }
  short* As = (short*)smem;
  short* Bs = (short*)(smem + 18432);
  if (bx < 132){
    int bxx = bx - 4;
    int zz = bxx>>6, rem = bxx&63;
    mfma_body(As, Bs, zz ? query_col : query_row, ipw + (zz?65536:0), ipb + (zz?256:0),
              zz ? qc : qr, rem&31, rem>>5, scaling, 0);
  } else {
    int bxx = bx - 132;
    mfma_body(As, Bs, value, ipw+262144, ipb+1024, (float*)vpB, bxx&127, bxx>>7, 1.f, 4);
  }
}

// ---------------- L3: scores + softmax (no-max), gate folded into K load; 4 waves/block ---------
__global__ __launch_bounds__(256) void k_attn(
    const float* __restrict__ qr, const float* __restrict__ kr0,
    const float* __restrict__ qc, const float* __restrict__ kc0,
    const float* __restrict__ gate,
    short* __restrict__ arB, short* __restrict__ acB){
  int tid = threadIdx.x;
  int lane = tid & 63, wave = tid >> 6;
  int tblk = blockIdx.x*4 + wave, n = blockIdx.y, z = blockIdx.z;
  int isCol = z >> 2, b = z & 3;
  const float* q  = isCol ? qc : qr;
  const float* kk = isCol ? kc0 : kr0;
  short* dst = isCol ? acB : arB;
  int bn = b*8 + n;
  float4 kreg[8];
  {
    const float4* kp = (const float4*)(kk + ((size_t)(b*64 + lane))*256 + n*32);
    const float4* gp = (const float4*)(gate + (size_t)b*256 + n*32);
    #pragma unroll
    for (int i=0;i<8;i++){
      float4 kv = kp[i], gv = gp[i];
      kreg[i] = make_float4(kv.x*gv.x, kv.y*gv.y, kv.z*gv.z, kv.w*gv.w);
    }
  }
  size_t qbase = ((size_t)(b*1024) + tblk*16)*256 + n*32;
  for (int i=0;i<16;i+=2){
    const float4* qp0 = (const float4*)(q + qbase + (size_t)i*256);
    const float4* qp1 = (const float4*)(q + qbase + (size_t)(i+1)*256);
    float s0 = 0.f, s1 = 0.f;
    #pragma unroll
    for (int j=0;j<8;j++){
      float4 a = qp0[j], c = qp1[j];
      s0 += a.x*kreg[j].x + a.y*kreg[j].y + a.z*kreg[j].z + a.w*kreg[j].w;
      s1 += c.x*kreg[j].x + c.y*kreg[j].y + c.z*kreg[j].z + c.w*kreg[j].w;
    }
    float e0 = __expf(s0), e1 = __expf(s1);
    float sm0 = e0, sm1 = e1;
    #pragma unroll
    for (int off=32; off; off>>=1){
      sm0 += __shfl_xor(sm0, off);
      sm1 += __shfl_xor(sm1, off);
    }
    size_t off_ = ((size_t)bn*1024 + tblk*16 + i)*64 + lane;
    dst[off_]      = f2bf(e0 / sm0);
    dst[off_ + 64] = f2bf(e1 / sm1);
  }
}

// ---------------- L4: core contraction, w split across waves, t-tile 32, 4-deep V ring ----------
__global__ __launch_bounds__(256) void k_core3(
    const short* __restrict__ acB, const short* __restrict__ arB,
    const __hip_bfloat16* __restrict__ vpB, float* __restrict__ outp){
  __shared__ float ARs[64*36];       // [w][t], stride 36
  __shared__ float P[4][32*34];      // per-wave partial [t][d], stride 34
  int tid = threadIdx.x;
  int bn = blockIdx.x, tt = blockIdx.y;
  int b = bn>>3, n = bn&7;
  int t0 = tt*32;

  { // stage ARs[w][t] from bf16
    int w = tid&63, tg = (tid>>6)*8;
    const unsigned short* src = (const unsigned short*)arB + ((size_t)bn*1024 + t0 + tg)*64 + w;
    #pragma unroll
    for (int k=0;k<8;k++)
      ARs[w*36 + tg + k] = b2f_lo((unsigned)src[(size_t)k*64]);
  }

  int l = tid&63, wid = tid>>6, lo16 = l&15, g = l>>4, g4 = g*4;
  bf16x8 af[2][2];
  {
    const short* ab = acB + ((size_t)bn*1024 + t0 + lo16)*64 + g*8;
    #pragma unroll
    for (int ts=0; ts<2; ts++){
      af[ts][0] = *(const bf16x8*)(ab + ts*1024);
      af[ts][1] = *(const bf16x8*)(ab + ts*1024 + 32);
    }
  }
  __syncthreads();

  const short* vb = (const short*)vpB + (size_t)bn*131072 + (size_t)wid*32768 + lo16*64 + g*8;
  // 4-deep register prefetch ring over w-steps
  bf16x8 ring[4][4];
  #pragma unroll
  for (int s=0;s<4;s++){
    const short* p = vb + (size_t)s*2048;
    ring[s][0] = *(const bf16x8*)(p);
    ring[s][1] = *(const bf16x8*)(p + 32);
    ring[s][2] = *(const bf16x8*)(p + 1024);
    ring[s][3] = *(const bf16x8*)(p + 1056);
  }
  f32x4 o[2][2] = {};
  const f32x4 zz = {0.f,0.f,0.f,0.f};
  int wbase = wid*16;

  #pragma unroll
  for (int wi=0; wi<16; ++wi){
    const int slot = wi & 3;
    bf16x8 c0=ring[slot][0], c1=ring[slot][1], c2=ring[slot][2], c3=ring[slot][3];
    const short* pn = vb + (size_t)((wi+4)&15)*2048;
    ring[slot][0] = *(const bf16x8*)(pn);
    ring[slot][1] = *(const bf16x8*)(pn + 32);
    ring[slot][2] = *(const bf16x8*)(pn + 1024);
    ring[slot][3] = *(const bf16x8*)(pn + 1056);
    int wg = wbase + wi;
    #pragma unroll
    for (int ts=0; ts<2; ts++){
      f32x4 mlo = __builtin_amdgcn_mfma_f32_16x16x32_bf16(af[ts][0], c0, zz, 0,0,0);
      mlo = __builtin_amdgcn_mfma_f32_16x16x32_bf16(af[ts][1], c1, mlo, 0,0,0);
      f32x4 mhi = __builtin_amdgcn_mfma_f32_16x16x32_bf16(af[ts][0], c2, zz, 0,0,0);
      mhi = __builtin_amdgcn_mfma_f32_16x16x32_bf16(af[ts][1], c3, mhi, 0,0,0);
      f32x4 ar4 = *(const f32x4*)&ARs[wg*36 + ts*16 + g4];
      #pragma unroll
      for (int r=0;r<4;r++){ o[ts][0][r] += ar4[r]*mlo[r]; o[ts][1][r] += ar4[r]*mhi[r]; }
    }
  }

  #pragma unroll
  for (int ts=0; ts<2; ts++)
    #pragma unroll
    for (int dh=0; dh<2; dh++)
      #pragma unroll
      for (int r=0;r<4;r++)
        P[wid][(ts*16 + g4 + r)*34 + dh*16 + lo16] = o[ts][dh][r];
  __syncthreads();

  float* obase = outp + ((size_t)b*1024 + t0)*256 + n*32;
  #pragma unroll
  for (int k=0;k<4;k++){
    int idx = k*256 + tid;
    int t = idx>>5, d = idx&31;
    float s = P[0][t*34+d] + P[1][t*34+d] + P[2][t*34+d] + P[3][t*34+d];
    obase[(size_t)t*256 + d] = s;
  }
}

// ---------------- L5: final out-projection (bx<64) || grid outer-product (bx>=64) -------------
__global__ __launch_bounds__(256) void k_fat2(
    const float* __restrict__ outp, const float* __restrict__ out_w,
    const float* __restrict__ out_b, float* __restrict__ out,
    const short* __restrict__ acB, const short* __restrict__ arB,
    float* __restrict__ gout){
  __shared__ __align__(16) char smem[36864];
  int bx = blockIdx.x;
  if (bx < 64){
    short* As = (short*)smem;
    short* Bs = (short*)(smem + 18432);
    mfma_body(As, Bs, outp, out_w, out_b, out, bx&31, bx>>5, 1.f, 3);
    return;
  }
  float* acs = (float*)smem;            // 2048 floats
  float* ars = (float*)(smem + 8192);   // 2048 floats
  int bxx = bx - 64;
  int tid = threadIdx.x, tg = bxx&255, b = bxx>>8;
  int t0 = tg*4;
  {
    int idx = tid*8;
    int n = idx>>8, t = (idx>>6)&3, x = idx&63;
    size_t soff = ((size_t)(b*8+n)*1024 + t0+t)*64 + x;
    uint4 av = *(const uint4*)(acB + soff);
    float* ad = &acs[(n*4+t)*64 + x];
    ad[0]=b2f_lo(av.x); ad[1]=b2f_hi(av.x); ad[2]=b2f_lo(av.y); ad[3]=b2f_hi(av.y);
    ad[4]=b2f_lo(av.z); ad[5]=b2f_hi(av.z); ad[6]=b2f_lo(av.w); ad[7]=b2f_hi(av.w);
    uint4 rv = *(const uint4*)(arB + soff);
    float* rd = &ars[(n*4+t)*64 + x];
    rd[0]=b2f_lo(rv.x); rd[1]=b2f_hi(rv.x); rd[2]=b2f_lo(rv.y); rd[3]=b2f_hi(rv.y);
    rd[4]=b2f_lo(rv.z); rd[5]=b2f_hi(rv.z); rd[6]=b2f_lo(rv.w); rd[7]=b2f_hi(rv.w);
  }
  __syncthreads();
  int t_ = tid>>6, l = tid&63;
  int wg = l&3, hsel = l>>2;
  float acc[4][16];
  #pragma unroll
  for (int i=0;i<4;i++)
    #pragma unroll
    for (int j=0;j<16;j++) acc[i][j] = 0.f;
  #pragma unroll
  for (int n=0;n<8;n++){
    float4 a4 = *(const float4*)&acs[(n*4+t_)*64 + hsel*4];
    const float4* rb = (const float4*)&ars[(n*4+t_)*64 + wg*16];
    float4 r0 = rb[0], r1 = rb[1], r2 = rb[2], r3 = rb[3];
    float rr[16] = {r0.x,r0.y,r0.z,r0.w, r1.x,r1.y,r1.z,r1.w,
                    r2.x,r2.y,r2.z,r2.w, r3.x,r3.y,r3.z,r3.w};
    float aa[4] = {a4.x, a4.y, a4.z, a4.w};
    #pragma unroll
    for (int i=0;i<4;i++)
      #pragma unroll
      for (int j=0;j<16;j++) acc[i][j] += aa[i]*rr[j];
  }
  const float inv = 0.125f;
  float* dstbase = gout + ((size_t)(t0+t_)*4 + b)*4096;
  #pragma unroll
  for (int i=0;i<4;i++){
    float* dst = dstbase + (hsel*4+i)*64 + wg*16;
    #pragma unroll
    for (int jq=0;jq<4;jq++)
      *(float4*)&dst[jq*4] = make_float4(acc[i][jq*4]*inv, acc[i][jq*4+1]*inv,
                                         acc[i][jq*4+2]*inv, acc[i][jq*4+3]*inv);
  }
}

// ---------------- host ----------------
extern "C" void kernel_launch(void* const* d_in, const int* in_sizes, int n_in,
                              void* d_out, int out_size, void* d_ws, size_t ws_size,
                              hipStream_t stream){
  const float* query_row = (const float*)d_in[0];
  const float* query_col = (const float*)d_in[1];
  const float* key_row   = (const float*)d_in[2];
  const float* key_col   = (const float*)d_in[3];
  const float* value     = (const float*)d_in[4];
  const float* ipw       = (const float*)d_in[5];
  const float* ipb       = (const float*)d_in[6];
  const float* out_w     = (const float*)d_in[7];
  const float* out_b     = (const float*)d_in[8];
  const float* lin_w     = (const float*)d_in[9];
  const float* lin_b     = (const float*)d_in[10];
  float* out = (float*)d_out;
  float* ws  = (float*)d_ws;

  float* vpart = ws;                    // 32768
  float* gate  = ws + 32768;            // 1024
  float* kr0   = ws + 33792;            // 65536
  float* kc0   = ws + 99328;            // 65536
  float* qr    = ws + 164864;           // 1048576
  float* qc    = ws + 1213440;          // 1048576
  __hip_bfloat16* vpB = (__hip_bfloat16*)(ws + 2262016);  // 4194304 bf16 (2097152 floats)
  short* arB  = (short*)(ws + 4359168);                    // 2097152 bf16 (1048576 floats)
  short* acB  = (short*)(ws + 5407744);                    // 2097152 bf16 (1048576 floats)
  float* outp = ws + 6456320;                              // 1048576 (end: 7504896 floats)

  const float scaling = 0.17677669529663687f;  // 32^-0.5

  // L1: reductions + fused kr0/kc0 projection
  hipLaunchKernelGGL(k_reduce, dim3(640), dim3(256), 0, stream,
                     value, key_row, key_col, ipw, ipb, vpart, kr0, kc0);

  // L2: gate || qr/qc projection || value projection+pack
  hipLaunchKernelGGL(k_proj, dim3(388), dim3(256), 0, stream,
                     value, query_row, query_col, ipw, ipb,
                     vpart, lin_w, lin_b, gate, qr, qc, (short*)vpB, scaling);

  // L3: both attentions (gate folded into K load; 4 waves/block)
  hipLaunchKernelGGL(k_attn, dim3(16,8,8), dim3(256), 0, stream,
                     qr, kr0, qc, kc0, gate, arB, acB);

  // L4: core contraction
  hipLaunchKernelGGL(k_core3, dim3(32,32), dim3(256), 0, stream, acB, arB, vpB, outp);

  // L5: final out-projection || grid outer-product
  hipLaunchKernelGGL(k_fat2, dim3(1088), dim3(256), 0, stream,
                     outp, out_w, out_b, out, acB, arB, out + 1048576);
}

// Round 15
// 115.935 us; speedup vs baseline: 1.1486x; 1.1486x over previous
//
#include <hip/hip_runtime.h>
#include <hip/hip_bf16.h>
#include <math.h>

// Dims: B=4, T=1024, H=W=64, C=256, nh=8, hd=32
using bf16x8 = __attribute__((ext_vector_type(8))) short;
using f32x4  = __attribute__((ext_vector_type(4))) float;
using s16x4  = __attribute__((ext_vector_type(4))) short;

static __device__ __forceinline__ float sigmoidf_(float x){ return 1.f/(1.f+__expf(-x)); }
static __device__ __forceinline__ unsigned f2bfu(float f){
  union { float f; unsigned u; } x; x.f = f;
  return (x.u + 0x7FFFu + ((x.u>>16)&1u)) >> 16;
}
static __device__ __forceinline__ short f2bf(float f){ return (short)f2bfu(f); }
// packed bf16 convert: single v_cvt_pk_bf16_f32 (RNE), low short = first arg
static __device__ __forceinline__ unsigned pack2bf(float lo, float hi){
  __hip_bfloat162 h = __float22bfloat162_rn(make_float2(lo, hi));
  unsigned r; __builtin_memcpy(&r, &h, 4);
  return r;
}
static __device__ __forceinline__ float b2f_lo(unsigned u){ union{unsigned u; float f;}x; x.u = u<<16; return x.f; }
static __device__ __forceinline__ float b2f_hi(unsigned u){ union{unsigned u; float f;}x; x.u = u & 0xFFFF0000u; return x.f; }

// ---------------- bf16 MFMA GEMM body ----------------
// mode 0: *scale ; mode 3: transposed [t][b][c] store ; mode 4: value-proj -> vpB bf16 [bn][w][d][h]
__device__ __forceinline__ void mfma_body(short* As, short* Bs,
    const float* __restrict__ X, const float* __restrict__ Wm,
    const float* __restrict__ bias, float* __restrict__ Y,
    int bxm, int bxn, float scale, int mode){
  int tid = threadIdx.x;
  int m0 = bxm*128, n0 = bxn*128;
  int l = tid&63, wid = tid>>6, lo16 = l&15, g = l>>4;
  int wm = wid>>1, wn = wid&1;
  f32x4 acc[4][4] = {};
  int srow = tid>>1, skq = (tid&1)*32;
  size_t arow;
  int vb_ = 0, vw0 = 0;
  if (mode==4){
    vb_ = bxm>>5; vw0 = (bxm&31)*2;
    arow = (size_t)(vb_*4096 + (srow&63)*64 + vw0 + (srow>>6));
  } else arow = (size_t)(m0+srow);
  const float4* sa = (const float4*)(X + arow*256 + skq);
  const float4* sb = (const float4*)(Wm + (size_t)(n0+srow)*256 + skq);
  int4* da = (int4*)&As[srow*72 + skq];
  int4* db = (int4*)&Bs[srow*72 + skq];
  for (int k0=0;k0<4;k0++){
    __syncthreads();
    #pragma unroll
    for (int j=0;j<4;j++){
      float4 v0 = sa[2*j], v1 = sa[2*j+1];
      int4 wv;
      wv.x = (int)pack2bf(v0.x, v0.y); wv.y = (int)pack2bf(v0.z, v0.w);
      wv.z = (int)pack2bf(v1.x, v1.y); wv.w = (int)pack2bf(v1.z, v1.w);
      da[j] = wv;
      float4 u0 = sb[2*j], u1 = sb[2*j+1];
      int4 xv;
      xv.x = (int)pack2bf(u0.x, u0.y); xv.y = (int)pack2bf(u0.z, u0.w);
      xv.z = (int)pack2bf(u1.x, u1.y); xv.w = (int)pack2bf(u1.z, u1.w);
      db[j] = xv;
    }
    sa += 16; sb += 16;
    __syncthreads();
    bf16x8 af[4][2], bfr[4][2];
    #pragma unroll
    for (int mt=0;mt<4;mt++)
      #pragma unroll
      for (int c=0;c<2;c++)
        af[mt][c] = *(const bf16x8*)&As[(wm*64 + mt*16 + lo16)*72 + c*32 + g*8];
    #pragma unroll
    for (int nt=0;nt<4;nt++)
      #pragma unroll
      for (int c=0;c<2;c++)
        bfr[nt][c] = *(const bf16x8*)&Bs[(wn*64 + nt*16 + lo16)*72 + c*32 + g*8];
    #pragma unroll
    for (int mt=0;mt<4;mt++)
      #pragma unroll
      for (int nt=0;nt<4;nt++){
        acc[mt][nt] = __builtin_amdgcn_mfma_f32_16x16x32_bf16(af[mt][0], bfr[nt][0], acc[mt][nt], 0,0,0);
        acc[mt][nt] = __builtin_amdgcn_mfma_f32_16x16x32_bf16(af[mt][1], bfr[nt][1], acc[mt][nt], 0,0,0);
      }
  }
  if (mode==4){
    short* vdst = (short*)Y;
    int w = vw0 + wm;
    #pragma unroll
    for (int nt=0;nt<4;nt++){
      int col = n0 + wn*64 + nt*16 + lo16;
      float bv = bias[col];
      int n = col>>5, d = col&31;
      size_t base = (size_t)(vb_*8+n)*131072 + (size_t)w*2048 + d*64;
      #pragma unroll
      for (int mt=0;mt<4;mt++){
        int h0 = mt*16 + g*4;
        s16x4 s;
        #pragma unroll
        for (int r=0;r<4;r++) s[r] = f2bf(acc[mt][nt][r] + bv);
        *(s16x4*)(vdst + base + h0) = s;
      }
    }
  } else if (mode==3){
    #pragma unroll
    for (int nt=0;nt<4;nt++){
      int col = n0 + wn*64 + nt*16 + lo16;
      float bv = bias[col];
      #pragma unroll
      for (int mt=0;mt<4;mt++){
        int row = m0 + wm*64 + mt*16 + g*4;
        #pragma unroll
        for (int r=0;r<4;r++){
          int rr = row + r;
          Y[((size_t)((rr&1023)*4 + (rr>>10)))*256 + col] = acc[mt][nt][r] + bv;
        }
      }
    }
  } else {
    #pragma unroll
    for (int nt=0;nt<4;nt++){
      int col = n0 + wn*64 + nt*16 + lo16;
      float bv = bias[col];
      #pragma unroll
      for (int mt=0;mt<4;mt++){
        int row = m0 + wm*64 + mt*16 + g*4;
        #pragma unroll
        for (int r=0;r<4;r++){
          float y = acc[mt][nt][r] + bv;
          if (mode==0) y *= scale;
          Y[(size_t)(row+r)*256 + col] = y;
        }
      }
    }
  }
}

// ---------------- krkc body (flat 256 threads): f32 GEMM with in-block gate ----------------
__device__ __forceinline__ void krkc_body(char* smem,
    const float* __restrict__ krm, const float* __restrict__ kcm,
    const float* __restrict__ ipw, const float* __restrict__ ipb,
    const float* __restrict__ vpart, const float* __restrict__ lin_w,
    const float* __restrict__ lin_b,
    float* __restrict__ kr, float* __restrict__ kc,
    int b, int ny, int z){
  const float* X; const float* Wm; const float* bias; float* Y;
  if (z==0){ X=krm; Wm=ipw+131072; bias=ipb+512; Y=kr; }
  else     { X=kcm; Wm=ipw+196608; bias=ipb+768; Y=kc; }
  float* Ast = (float*)smem;             // 32*68
  float* Bst = (float*)(smem + 8704);    // 32*68
  float* va  = (float*)(smem + 17408);   // 256
  float* gsh = (float*)(smem + 18432);   // 64
  int tid = threadIdx.x;
  int tx = tid&15, ty = tid>>4;
  int m0 = b*64, n0 = ny*64;
  {
    float s = 0.f;
    #pragma unroll
    for (int i=0;i<32;i++) s += vpart[(size_t)(b*32+i)*256 + tid];
    va[tid] = s * (1.f/4096.f);
  }
  __syncthreads();
  {
    int j = tid>>2, kq = tid&3;
    const float* wrow = lin_w + (size_t)(n0+j)*256 + kq*64;
    const float* vap  = va + kq*64;
    float part = 0.f;
    #pragma unroll
    for (int k=0;k<64;k++) part += vap[k]*wrow[k];
    part += __shfl_xor(part, 1);
    part += __shfl_xor(part, 2);
    if (kq==0) gsh[j] = sigmoidf_(part + lin_b[n0+j]);
  }
  float acc[4][4];
  #pragma unroll
  for (int i=0;i<4;i++)
    #pragma unroll
    for (int j=0;j<4;j++) acc[i][j] = 0.f;

  for (int k0=0;k0<256;k0+=32){
    __syncthreads();
    #pragma unroll
    for (int p=0;p<2;p++){
      int pos = tid + p*256;
      int r = pos>>3, kq = pos&7;
      float4 xa = *(const float4*)&X[(size_t)(m0+r)*256 + k0 + kq*4];
      Ast[(kq*4+0)*68+r]=xa.x; Ast[(kq*4+1)*68+r]=xa.y;
      Ast[(kq*4+2)*68+r]=xa.z; Ast[(kq*4+3)*68+r]=xa.w;
      float4 wb = *(const float4*)&Wm[(size_t)(n0+r)*256 + k0 + kq*4];
      Bst[(kq*4+0)*68+r]=wb.x; Bst[(kq*4+1)*68+r]=wb.y;
      Bst[(kq*4+2)*68+r]=wb.z; Bst[(kq*4+3)*68+r]=wb.w;
    }
    __syncthreads();
    #pragma unroll
    for (int k=0;k<32;k++){
      float4 a  = *(const float4*)&Ast[k*68 + ty*4];
      float4 bv = *(const float4*)&Bst[k*68 + tx*4];
      acc[0][0]+=a.x*bv.x; acc[0][1]+=a.x*bv.y; acc[0][2]+=a.x*bv.z; acc[0][3]+=a.x*bv.w;
      acc[1][0]+=a.y*bv.x; acc[1][1]+=a.y*bv.y; acc[1][2]+=a.y*bv.z; acc[1][3]+=a.y*bv.w;
      acc[2][0]+=a.z*bv.x; acc[2][1]+=a.z*bv.y; acc[2][2]+=a.z*bv.z; acc[2][3]+=a.z*bv.w;
      acc[3][0]+=a.w*bv.x; acc[3][1]+=a.w*bv.y; acc[3][2]+=a.w*bv.z; acc[3][3]+=a.w*bv.w;
    }
  }
  float4 b4 = *(const float4*)&bias[n0 + tx*4];
  float4 g4 = *(const float4*)&gsh[tx*4];
  #pragma unroll
  for (int i=0;i<4;i++){
    int row = m0 + ty*4 + i;
    float4 y = make_float4((acc[i][0]+b4.x)*g4.x, (acc[i][1]+b4.y)*g4.y,
                           (acc[i][2]+b4.z)*g4.z, (acc[i][3]+b4.w)*g4.w);
    *(float4*)&Y[(size_t)row*256 + n0 + tx*4] = y;
  }
}

// ---------------- L1: reductions only (640 blocks) ----------------
__global__ __launch_bounds__(256) void k_reduce(
    const float* __restrict__ value, const float* __restrict__ key_row,
    const float* __restrict__ key_col, float* __restrict__ vpart,
    float* __restrict__ krm, float* __restrict__ kcm){
  __shared__ float red[1024];
  int bx = blockIdx.x, c = threadIdx.x;
  int cq = c & 63, rg = c >> 6;
  float4 s4 = make_float4(0.f,0.f,0.f,0.f);
  float oscale; float* outp_; size_t obase;
  if (bx < 128){
    int b = bx >> 5, chunk = bx & 31;
    const float4* p = (const float4*)(value + ((size_t)(b*4096 + chunk*128 + rg))*256) + cq;
    #pragma unroll 8
    for (int i=0;i<32;i++){
      float4 v = p[(size_t)i*256];
      s4.x+=v.x; s4.y+=v.y; s4.z+=v.z; s4.w+=v.w;
    }
    oscale = 1.f; outp_ = vpart; obase = (size_t)bx*256;
  } else if (bx < 384){
    int idx = bx - 128;
    int b = idx >> 6, w = idx & 63;
    const float4* p = (const float4*)(key_row + ((size_t)(b*4096 + w))*256) + cq;
    #pragma unroll 8
    for (int i=0;i<16;i++){
      float4 v = p[(size_t)(rg + 4*i)*4096];
      s4.x+=v.x; s4.y+=v.y; s4.z+=v.z; s4.w+=v.w;
    }
    oscale = 1.f/64.f; outp_ = krm; obase = (size_t)idx*256;
  } else {
    int idx = bx - 384;
    int b = idx >> 6, h = idx & 63;
    const float4* p = (const float4*)(key_col + ((size_t)((b*64+h)*64))*256) + cq;
    #pragma unroll 8
    for (int i=0;i<16;i++){
      float4 v = p[(size_t)(rg + 4*i)*64];
      s4.x+=v.x; s4.y+=v.y; s4.z+=v.z; s4.w+=v.w;
    }
    oscale = 1.f/64.f; outp_ = kcm; obase = (size_t)idx*256;
  }
  *(float4*)&red[rg*256 + cq*4] = s4;
  __syncthreads();
  if (c < 64){
    float4 a0 = *(float4*)&red[c*4];
    float4 a1 = *(float4*)&red[256 + c*4];
    float4 a2 = *(float4*)&red[512 + c*4];
    float4 a3 = *(float4*)&red[768 + c*4];
    float4 o = make_float4((a0.x+a1.x+a2.x+a3.x)*oscale, (a0.y+a1.y+a2.y+a3.y)*oscale,
                           (a0.z+a1.z+a2.z+a3.z)*oscale, (a0.w+a1.w+a2.w+a3.w)*oscale);
    *(float4*)&outp_[obase + c*4] = o;
  }
}

// ---------------- L2: krkc (bx<32) || qr/qc MFMA (32..159) || vp MFMA (160..415) ----------------
__global__ __launch_bounds__(256) void k_proj(
    const float* __restrict__ krm, const float* __restrict__ kcm,
    const float* __restrict__ value,
    const float* __restrict__ query_row, const float* __restrict__ query_col,
    const float* __restrict__ ipw, const float* __restrict__ ipb,
    const float* __restrict__ vpart, const float* __restrict__ lin_w,
    const float* __restrict__ lin_b,
    float* __restrict__ kr, float* __restrict__ kc,
    float* __restrict__ qr, float* __restrict__ qc,
    short* __restrict__ vpB, float scaling){
  __shared__ __align__(16) char smem[36864];
  int bx = blockIdx.x;
  if (bx < 32){
    int z = bx>>4, rem = bx&15, b = rem&3, ny = rem>>2;
    krkc_body(smem, krm, kcm, ipw, ipb, vpart, lin_w, lin_b, kr, kc, b, ny, z);
    return;
  }
  short* As = (short*)smem;
  short* Bs = (short*)(smem + 18432);
  if (bx < 160){
    int bxx = bx - 32;
    int zz = bxx>>6, rem = bxx&63;
    mfma_body(As, Bs, zz ? query_col : query_row, ipw + (zz?65536:0), ipb + (zz?256:0),
              zz ? qc : qr, rem&31, rem>>5, scaling, 0);
  } else {
    int bxx = bx - 160;
    mfma_body(As, Bs, value, ipw+262144, ipb+1024, (float*)vpB, bxx&127, bxx>>7, 1.f, 4);
  }
}

// ---------------- L3: scores + softmax (no-max; |s|<~1), 2-t ILP; bf16 outputs ----------------
__global__ void k_attn(const float* __restrict__ qr, const float* __restrict__ kr,
                       const float* __restrict__ qc, const float* __restrict__ kc,
                       short* __restrict__ arB, short* __restrict__ acB){
  int lane = threadIdx.x;
  int tblk = blockIdx.x, n = blockIdx.y, z = blockIdx.z;
  int isCol = z >> 2, b = z & 3;
  const float* q  = isCol ? qc : qr;
  const float* kk = isCol ? kc : kr;
  short* dst = isCol ? acB : arB;
  int bn = b*8 + n;
  float4 kreg[8];
  const float4* kp = (const float4*)(kk + ((size_t)(b*64 + lane))*256 + n*32);
  #pragma unroll
  for (int i=0;i<8;i++) kreg[i] = kp[i];
  size_t qbase = ((size_t)(b*1024) + tblk*16)*256 + n*32;
  for (int i=0;i<16;i+=2){
    const float4* qp0 = (const float4*)(q + qbase + (size_t)i*256);
    const float4* qp1 = (const float4*)(q + qbase + (size_t)(i+1)*256);
    float s0 = 0.f, s1 = 0.f;
    #pragma unroll
    for (int j=0;j<8;j++){
      float4 a = qp0[j], c = qp1[j];
      s0 += a.x*kreg[j].x + a.y*kreg[j].y + a.z*kreg[j].z + a.w*kreg[j].w;
      s1 += c.x*kreg[j].x + c.y*kreg[j].y + c.z*kreg[j].z + c.w*kreg[j].w;
    }
    float e0 = __expf(s0), e1 = __expf(s1);
    float sm0 = e0, sm1 = e1;
    #pragma unroll
    for (int off=32; off; off>>=1){
      sm0 += __shfl_xor(sm0, off);
      sm1 += __shfl_xor(sm1, off);
    }
    size_t off_ = ((size_t)bn*1024 + tblk*16 + i)*64 + lane;
    dst[off_]      = f2bf(e0 / sm0);
    dst[off_ + 64] = f2bf(e1 / sm1);
  }
}

// ---------------- L4: core contraction, w split across waves, t-tile 32, 4-deep V ring ----------
__global__ __launch_bounds__(256) void k_core3(
    const short* __restrict__ acB, const short* __restrict__ arB,
    const __hip_bfloat16* __restrict__ vpB, float* __restrict__ outp){
  __shared__ float ARs[64*36];       // [w][t], stride 36
  __shared__ float P[4][32*34];      // per-wave partial [t][d], stride 34
  int tid = threadIdx.x;
  int bn = blockIdx.x, tt = blockIdx.y;
  int b = bn>>3, n = bn&7;
  int t0 = tt*32;

  { // stage ARs[w][t] from bf16
    int w = tid&63, tg = (tid>>6)*8;
    const unsigned short* src = (const unsigned short*)arB + ((size_t)bn*1024 + t0 + tg)*64 + w;
    #pragma unroll
    for (int k=0;k<8;k++)
      ARs[w*36 + tg + k] = b2f_lo((unsigned)src[(size_t)k*64]);
  }

  int l = tid&63, wid = tid>>6, lo16 = l&15, g = l>>4, g4 = g*4;
  bf16x8 af[2][2];
  {
    const short* ab = acB + ((size_t)bn*1024 + t0 + lo16)*64 + g*8;
    #pragma unroll
    for (int ts=0; ts<2; ts++){
      af[ts][0] = *(const bf16x8*)(ab + ts*1024);
      af[ts][1] = *(const bf16x8*)(ab + ts*1024 + 32);
    }
  }
  __syncthreads();

  const short* vb = (const short*)vpB + (size_t)bn*131072 + (size_t)wid*32768 + lo16*64 + g*8;
  // 4-deep register prefetch ring over w-steps
  bf16x8 ring[4][4];
  #pragma unroll
  for (int s=0;s<4;s++){
    const short* p = vb + (size_t)s*2048;
    ring[s][0] = *(const bf16x8*)(p);
    ring[s][1] = *(const bf16x8*)(p + 32);
    ring[s][2] = *(const bf16x8*)(p + 1024);
    ring[s][3] = *(const bf16x8*)(p + 1056);
  }
  f32x4 o[2][2] = {};
  const f32x4 zz = {0.f,0.f,0.f,0.f};
  int wbase = wid*16;

  #pragma unroll
  for (int wi=0; wi<16; ++wi){
    const int slot = wi & 3;
    bf16x8 c0=ring[slot][0], c1=ring[slot][1], c2=ring[slot][2], c3=ring[slot][3];
    const short* pn = vb + (size_t)((wi+4)&15)*2048;
    ring[slot][0] = *(const bf16x8*)(pn);
    ring[slot][1] = *(const bf16x8*)(pn + 32);
    ring[slot][2] = *(const bf16x8*)(pn + 1024);
    ring[slot][3] = *(const bf16x8*)(pn + 1056);
    int wg = wbase + wi;
    #pragma unroll
    for (int ts=0; ts<2; ts++){
      f32x4 mlo = __builtin_amdgcn_mfma_f32_16x16x32_bf16(af[ts][0], c0, zz, 0,0,0);
      mlo = __builtin_amdgcn_mfma_f32_16x16x32_bf16(af[ts][1], c1, mlo, 0,0,0);
      f32x4 mhi = __builtin_amdgcn_mfma_f32_16x16x32_bf16(af[ts][0], c2, zz, 0,0,0);
      mhi = __builtin_amdgcn_mfma_f32_16x16x32_bf16(af[ts][1], c3, mhi, 0,0,0);
      f32x4 ar4 = *(const f32x4*)&ARs[wg*36 + ts*16 + g4];
      #pragma unroll
      for (int r=0;r<4;r++){ o[ts][0][r] += ar4[r]*mlo[r]; o[ts][1][r] += ar4[r]*mhi[r]; }
    }
  }

  #pragma unroll
  for (int ts=0; ts<2; ts++)
    #pragma unroll
    for (int dh=0; dh<2; dh++)
      #pragma unroll
      for (int r=0;r<4;r++)
        P[wid][(ts*16 + g4 + r)*34 + dh*16 + lo16] = o[ts][dh][r];
  __syncthreads();

  float* obase = outp + ((size_t)b*1024 + t0)*256 + n*32;
  #pragma unroll
  for (int k=0;k<4;k++){
    int idx = k*256 + tid;
    int t = idx>>5, d = idx&31;
    float s = P[0][t*34+d] + P[1][t*34+d] + P[2][t*34+d] + P[3][t*34+d];
    obase[(size_t)t*256 + d] = s;
  }
}

// ---------------- L5: final out-projection (bx<64) || grid outer-product (bx>=64) -------------
__global__ __launch_bounds__(256) void k_fat2(
    const float* __restrict__ outp, const float* __restrict__ out_w,
    const float* __restrict__ out_b, float* __restrict__ out,
    const short* __restrict__ acB, const short* __restrict__ arB,
    float* __restrict__ gout){
  __shared__ __align__(16) char smem[36864];
  int bx = blockIdx.x;
  if (bx < 64){
    short* As = (short*)smem;
    short* Bs = (short*)(smem + 18432);
    mfma_body(As, Bs, outp, out_w, out_b, out, bx&31, bx>>5, 1.f, 3);
    return;
  }
  float* acs = (float*)smem;            // 2048 floats
  float* ars = (float*)(smem + 8192);   // 2048 floats
  int bxx = bx - 64;
  int tid = threadIdx.x, tg = bxx&255, b = bxx>>8;
  int t0 = tg*4;
  {
    int idx = tid*8;
    int n = idx>>8, t = (idx>>6)&3, x = idx&63;
    size_t soff = ((size_t)(b*8+n)*1024 + t0+t)*64 + x;
    uint4 av = *(const uint4*)(acB + soff);
    float* ad = &acs[(n*4+t)*64 + x];
    ad[0]=b2f_lo(av.x); ad[1]=b2f_hi(av.x); ad[2]=b2f_lo(av.y); ad[3]=b2f_hi(av.y);
    ad[4]=b2f_lo(av.z); ad[5]=b2f_hi(av.z); ad[6]=b2f_lo(av.w); ad[7]=b2f_hi(av.w);
    uint4 rv = *(const uint4*)(arB + soff);
    float* rd = &ars[(n*4+t)*64 + x];
    rd[0]=b2f_lo(rv.x); rd[1]=b2f_hi(rv.x); rd[2]=b2f_lo(rv.y); rd[3]=b2f_hi(rv.y);
    rd[4]=b2f_lo(rv.z); rd[5]=b2f_hi(rv.z); rd[6]=b2f_lo(rv.w); rd[7]=b2f_hi(rv.w);
  }
  __syncthreads();
  int t_ = tid>>6, l = tid&63;
  int wg = l&3, hsel = l>>2;
  float acc[4][16];
  #pragma unroll
  for (int i=0;i<4;i++)
    #pragma unroll
    for (int j=0;j<16;j++) acc[i][j] = 0.f;
  #pragma unroll
  for (int n=0;n<8;n++){
    float4 a4 = *(const float4*)&acs[(n*4+t_)*64 + hsel*4];
    const float4* rb = (const float4*)&ars[(n*4+t_)*64 + wg*16];
    float4 r0 = rb[0], r1 = rb[1], r2 = rb[2], r3 = rb[3];
    float rr[16] = {r0.x,r0.y,r0.z,r0.w, r1.x,r1.y,r1.z,r1.w,
                    r2.x,r2.y,r2.z,r2.w, r3.x,r3.y,r3.z,r3.w};
    float aa[4] = {a4.x, a4.y, a4.z, a4.w};
    #pragma unroll
    for (int i=0;i<4;i++)
      #pragma unroll
      for (int j=0;j<16;j++) acc[i][j] += aa[i]*rr[j];
  }
  const float inv = 0.125f;
  float* dstbase = gout + ((size_t)(t0+t_)*4 + b)*4096;
  #pragma unroll
  for (int i=0;i<4;i++){
    float* dst = dstbase + (hsel*4+i)*64 + wg*16;
    #pragma unroll
    for (int jq=0;jq<4;jq++)
      *(float4*)&dst[jq*4] = make_float4(acc[i][jq*4]*inv, acc[i][jq*4+1]*inv,
                                         acc[i][jq*4+2]*inv, acc[i][jq*4+3]*inv);
  }
}

// ---------------- host ----------------
extern "C" void kernel_launch(void* const* d_in, const int* in_sizes, int n_in,
                              void* d_out, int out_size, void* d_ws, size_t ws_size,
                              hipStream_t stream){
  const float* query_row = (const float*)d_in[0];
  const float* query_col = (const float*)d_in[1];
  const float* key_row   = (const float*)d_in[2];
  const float* key_col   = (const float*)d_in[3];
  const float* value     = (const float*)d_in[4];
  const float* ipw       = (const float*)d_in[5];
  const float* ipb       = (const float*)d_in[6];
  const float* out_w     = (const float*)d_in[7];
  const float* out_b     = (const float*)d_in[8];
  const float* lin_w     = (const float*)d_in[9];
  const float* lin_b     = (const float*)d_in[10];
  float* out = (float*)d_out;
  float* ws  = (float*)d_ws;

  float* vpart = ws;                    // 32768
  float* krm   = ws + 32768;            // 65536
  float* kcm   = ws + 98304;            // 65536
  float* kr    = ws + 163840;           // 65536
  float* kc    = ws + 229376;           // 65536
  float* qr    = ws + 294912;           // 1048576
  float* qc    = ws + 1343488;          // 1048576
  __hip_bfloat16* vpB = (__hip_bfloat16*)(ws + 2392064);  // 4194304 bf16 (2097152 floats)
  short* arB  = (short*)(ws + 4489216);                    // 2097152 bf16 (1048576 floats)
  short* acB  = (short*)(ws + 5537792);                    // 2097152 bf16 (1048576 floats)
  float* outp = ws + 6586368;                              // 1048576 (end: 7634944 floats)

  const float scaling = 0.17677669529663687f;  // 32^-0.5

  // L1: reductions only
  hipLaunchKernelGGL(k_reduce, dim3(640), dim3(256), 0, stream,
                     value, key_row, key_col, vpart, krm, kcm);

  // L2: krkc || qr/qc projection || value projection+pack
  hipLaunchKernelGGL(k_proj, dim3(416), dim3(256), 0, stream,
                     krm, kcm, value, query_row, query_col, ipw, ipb,
                     vpart, lin_w, lin_b, kr, kc, qr, qc, (short*)vpB, scaling);

  // L3: both attentions (bf16 outputs)
  hipLaunchKernelGGL(k_attn, dim3(64,8,8), dim3(64), 0, stream,
                     qr, kr, qc, kc, arB, acB);

  // L4: core contraction
  hipLaunchKernelGGL(k_core3, dim3(32,32), dim3(256), 0, stream, acB, arB, vpB, outp);

  // L5: final out-projection || grid outer-product
  hipLaunchKernelGGL(k_fat2, dim3(1088), dim3(256), 0, stream,
                     outp, out_w, out_b, out, acB, arB, out + 1048576);
}